// Round 1
// baseline (92.838 us; speedup 1.0000x reference)
//
#include <hip/hip_runtime.h>
#include <math.h>

#define NYX 192          // spatial Y = X = 192
#define NNODE 193        // node grid dim (Y+1)
#define L_NODES (193*193)
#define NPAIR 11
#define NB 2
#define NCH 12

__device__ __forceinline__ float sigmoidf_(float x) { return 1.0f / (1.0f + expf(-x)); }

__global__ __launch_bounds__(256) void sdice_main(const float* __restrict__ pred,
                                                  const float* __restrict__ labels,
                                                  const float* __restrict__ area,
                                                  float* __restrict__ ws)
{
    const int pair = blockIdx.z;
    const int b    = blockIdx.y;
    const int l    = blockIdx.x * blockDim.x + threadIdx.x;

    float num = 0.f, den = 0.f, bce = 0.f, cnt = 0.f;

    if (l < L_NODES) {
        const int j  = l / NNODE;
        const int ix = l - j * NNODE;

        float up[8], ul[8], ur[8];
        int byte = 0;
        #pragma unroll
        for (int c = 0; c < 2; ++c) {
            const int ch = pair + c;
            const size_t base = ((size_t)(b * NCH + ch)) * NYX * NYX;
            #pragma unroll
            for (int ky = 0; ky < 2; ++ky) {
                const int y = j - 1 + ky;
                #pragma unroll
                for (int kx = 0; kx < 2; ++kx) {
                    const int x = ix - 1 + kx;
                    const int k = c * 4 + ky * 2 + kx;
                    const bool inb = ((unsigned)y < NYX) && ((unsigned)x < NYX);
                    float pv = 0.f, lv = 0.f;
                    if (inb) {
                        const size_t off = base + (size_t)y * NYX + x;
                        pv = pred[off];
                        lv = labels[off];
                    }
                    up[k] = inb ? sigmoidf_(pv) : 0.0f;   // pad AFTER sigmoid -> literal 0
                    ur[k] = pv;                            // raw pred, pad 0
                    ul[k] = lv;                            // label, pad 0
                    byte |= ((int)lv) << k;
                }
            }
        }

        // w_lab = 1 - ||up - bits(byte)||/16 ; bits(byte)[k] == ul[k]
        float d2 = 0.f;
        #pragma unroll
        for (int k = 0; k < 8; ++k) { float d = up[k] - ul[k]; d2 += d * d; }
        const float w_lab = 1.0f - sqrtf(d2) * (1.0f / 16.0f);
        const float la = area[byte];
        num = w_lab * la;
        den = la;

        if (byte == 0 || byte == 255) {
            cnt = 1.f;
            float s = 0.f;
            #pragma unroll
            for (int k = 0; k < 8; ++k) {
                const float x = ur[k], y = ul[k];
                s += fmaxf(x, 0.f) - x * y + log1pf(expf(-fabsf(x)));
            }
            bce = s;
        }
    }

    // wave (64-lane) shuffle reduce, then cross-wave via LDS
    #pragma unroll
    for (int off = 32; off > 0; off >>= 1) {
        num += __shfl_down(num, off);
        den += __shfl_down(den, off);
        bce += __shfl_down(bce, off);
        cnt += __shfl_down(cnt, off);
    }
    __shared__ float red[4][4];
    const int lane = threadIdx.x & 63;
    const int wid  = threadIdx.x >> 6;
    if (lane == 0) { red[wid][0] = num; red[wid][1] = den; red[wid][2] = bce; red[wid][3] = cnt; }
    __syncthreads();
    if (threadIdx.x == 0) {
        float n = 0, d = 0, bc = 0, ct = 0;
        #pragma unroll
        for (int w = 0; w < 4; ++w) { n += red[w][0]; d += red[w][1]; bc += red[w][2]; ct += red[w][3]; }
        float* g = ws + (size_t)(pair * NB + b) * 4;
        atomicAdd(g + 0, n);
        atomicAdd(g + 1, d);
        atomicAdd(g + 2, bc);
        atomicAdd(g + 3, ct);
    }
}

__global__ void sdice_final(const float* __restrict__ ws,
                            const float* __restrict__ area,
                            float* __restrict__ out)
{
    if (threadIdx.x == 0 && blockIdx.x == 0) {
        const float a1 = area[1];             // pred_byte == 1 everywhere (see analysis)
        float dice_sum = 0.f, vol_sum = 0.f;
        for (int b = 0; b < NB; ++b) {
            float numb = 0.f, denb = 0.f, volb = 0.f;
            for (int p = 0; p < NPAIR; ++p) {
                const float* g = ws + (size_t)(p * NB + b) * 4;
                numb += 2.0f * g[0];
                denb += g[1] + (float)L_NODES * a1;
                volb += g[2] / (8.0f * g[3]);
            }
            dice_sum += 1.0f - (numb + 0.001f) / (denb + 0.001f);
            vol_sum  += volb;
        }
        out[0] = dice_sum / (float)NB + vol_sum / (float)NB;
    }
}

extern "C" void kernel_launch(void* const* d_in, const int* in_sizes, int n_in,
                              void* d_out, int out_size, void* d_ws, size_t ws_size,
                              hipStream_t stream) {
    const float* pred   = (const float*)d_in[0];
    const float* labels = (const float*)d_in[1];
    const float* area   = (const float*)d_in[2];
    float* out = (float*)d_out;
    float* ws  = (float*)d_ws;

    hipMemsetAsync(ws, 0, NPAIR * NB * 4 * sizeof(float), stream);

    dim3 grid((L_NODES + 255) / 256, NB, NPAIR);
    sdice_main<<<grid, dim3(256), 0, stream>>>(pred, labels, area, ws);
    sdice_final<<<1, 64, 0, stream>>>(ws, area, out);
}